// Round 7
// baseline (160.206 us; speedup 1.0000x reference)
//
#include <hip/hip_runtime.h>
#include <math.h>

#define SIDE 0.6

// ---------- fast f64 exp, |x| <= 350, rel err ~1e-15 (validated r3/r4) ----------
__device__ __forceinline__ double exp_fast(double x) {
    const double INVLN2 = 1.44269504088896338700e+00;
    const double LN2HI  = 6.93147180369123816490e-01;
    const double LN2LO  = 1.90821492927058770002e-10;
    const double kd = __builtin_rint(x * INVLN2);
    const int    k  = (int)kd;
    double r = __builtin_fma(-kd, LN2HI, x);
    r        = __builtin_fma(-kd, LN2LO, r);
    double p =               2.08767569878681e-09;
    p = __builtin_fma(p, r,  2.50521083854417e-08);
    p = __builtin_fma(p, r,  2.75573192239859e-07);
    p = __builtin_fma(p, r,  2.75573192239859e-06);
    p = __builtin_fma(p, r,  2.48015873015873e-05);
    p = __builtin_fma(p, r,  1.98412698412698e-04);
    p = __builtin_fma(p, r,  1.38888888888889e-03);
    p = __builtin_fma(p, r,  8.33333333333333e-03);
    p = __builtin_fma(p, r,  4.16666666666667e-02);
    p = __builtin_fma(p, r,  1.66666666666667e-01);
    p = __builtin_fma(p, r,  5.00000000000000e-01);
    p = __builtin_fma(p, r,  1.0);
    p = __builtin_fma(p, r,  1.0);
    const long long bits = (long long)(1023 + k) << 52;
    return p * __longlong_as_double(bits);
}

// ---------- fast f32 exp, |x| <= 40, rel err ~2e-7 (validated r5) ----------
__device__ __forceinline__ float exp_fast_f(float x) {
    const float kd = rintf(x * 1.44269504f);
    const int   k  = (int)kd;
    float r = __builtin_fmaf(-kd, 0.693359375f, x);
    r       = __builtin_fmaf(kd, 2.12194440e-4f, r);
    float p =                1.98412698e-4f;
    p = __builtin_fmaf(p, r, 1.38888889e-3f);
    p = __builtin_fmaf(p, r, 8.33333333e-3f);
    p = __builtin_fmaf(p, r, 4.16666667e-2f);
    p = __builtin_fmaf(p, r, 1.66666667e-1f);
    p = __builtin_fmaf(p, r, 5.00000000e-1f);
    p = __builtin_fmaf(p, r, 1.0f);
    p = __builtin_fmaf(p, r, 1.0f);
    return p * __int_as_float((127 + k) << 23);
}

#if __has_builtin(__builtin_amdgcn_rcpf)
__device__ __forceinline__ float rcp_nr(float x) {   // ~0.5 ulp: v_rcp + 1 NR
    float r = __builtin_amdgcn_rcpf(x);
    return __builtin_fmaf(__builtin_fmaf(-x, r, 1.0f), r, r);
}
#else
__device__ __forceinline__ float rcp_nr(float x) { return 1.0f / x; }
#endif

#define NIMP 16

// ============================================================================
// Kernel 1: thread-per-ray f32 fast path (64 rays per wave, 1 wave per block).
// Sequential scans in registers; CDF prefix E in LDS (stride 65); inputs
// chunk-staged via padded LDS (stride 17). Flip-risk rays -> list for f64 redo.
// ============================================================================
__global__ __launch_bounds__(64) void neus_fast_kernel(
    const float* __restrict__ rays_o,
    const float* __restrict__ rays_d,
    const float* __restrict__ z_vals,
    const float* __restrict__ sdf,
    const float* __restrict__ inv_s,
    float* __restrict__ out,
    unsigned* __restrict__ ctr,
    unsigned* __restrict__ list,
    unsigned cap, int B)
{
    __shared__ float zC[64][17];
    __shared__ float sC[64][17];
    __shared__ float iC[64][17];
    __shared__ float E[64 * 65];

    const int t    = threadIdx.x;            // 0..63 : local ray
    const int ray0 = blockIdx.x * 64;
    const int ray  = ray0 + t;
    const bool live = ray < B;
    const int eb   = t * 65;

    float ox = 0.f, oy = 0.f, oz = 0.f, dx = 0.f, dy = 0.f, dz = 1.f;
    if (live) {
        ox = rays_o[(size_t)ray * 3 + 0];
        oy = rays_o[(size_t)ray * 3 + 1];
        oz = rays_o[(size_t)ray * 3 + 2];
        dx = rays_d[(size_t)ray * 3 + 0];
        dy = rays_d[(size_t)ray * 3 + 1];
        dz = rays_d[(size_t)ray * 3 + 2];
    }

    E[eb] = 0.0f;

    float cum = 0.f, trans = 1.f, prevc = 0.f;
    float z0 = 0.f, s0 = 0.f, inner0 = 0.f;
    int flag = 0;

    // =================== pass A: weights -> prefix E ===================
    #pragma unroll 1
    for (int g = 0; g < 4; ++g) {
        const int jb = g * 16;
        // --- stage 64 rows x 16 cols (coalesced: 4 rows x 16 cols / iter) ---
        #pragma unroll
        for (int r4 = 0; r4 < 16; ++r4) {
            const int row = r4 * 4 + (t >> 4);
            const int col = t & 15;
            const int rr  = ray0 + row;
            const bool ok = rr < B;
            const size_t zi = (size_t)rr * 64 + jb + col;
            zC[row][col] = ok ? z_vals[zi] : 0.0f;
            sC[row][col] = ok ? sdf[zi]    : 0.0f;
            const int ic = jb + col;
            iC[row][col] = (ok && ic < 63) ? inv_s[(size_t)rr * 63 + ic] : 0.0f;
        }
        if (g < 3) {   // col 16 (z[jb+16], s[jb+16]) : one scattered load
            zC[t][16] = live ? z_vals[(size_t)ray * 64 + jb + 16] : 0.0f;
            sC[t][16] = live ? sdf   [(size_t)ray * 64 + jb + 16] : 0.0f;
        }
        __syncthreads();

        if (g == 0) {   // j=0 left endpoint
            z0 = zC[t][0]; s0 = sC[t][0];
            const float px = __builtin_fmaf(dx, z0, ox);
            const float py = __builtin_fmaf(dy, z0, oy);
            const float pz = __builtin_fmaf(dz, z0, oz);
            const float ax = fabsf(px), ay = fabsf(py), az = fabsf(pz);
            inner0 = (ax <= 0.6f && ay <= 0.6f && az <= 0.6f) ? 1.f : 0.f;
            flag |= (fabsf(ax - 0.6f) < 1e-5f) | (fabsf(ay - 0.6f) < 1e-5f) |
                    (fabsf(az - 0.6f) < 1e-5f);
        }

        #pragma unroll
        for (int e = 0; e < 16; ++e) {
            if (g == 3 && e >= 15) break;          // j max = 62
            const int j = jb + e;
            const float z1 = zC[t][e + 1];
            const float s1 = sC[t][e + 1];
            const float iv = iC[t][e];

            // inner at z1 + box band flag (reference: fma'd pts vs 0.6)
            const float px = __builtin_fmaf(dx, z1, ox);
            const float py = __builtin_fmaf(dy, z1, oy);
            const float pz = __builtin_fmaf(dz, z1, oz);
            const float ax = fabsf(px), ay = fabsf(py), az = fabsf(pz);
            const float inner1 = (ax <= 0.6f && ay <= 0.6f && az <= 0.6f) ? 1.f : 0.f;
            flag |= (fabsf(ax - 0.6f) < 1e-5f) | (fabsf(ay - 0.6f) < 1e-5f) |
                    (fabsf(az - 0.6f) < 1e-5f);

            const float inside = ((inner0 > 0.5f) || (inner1 > 0.5f)) ? 1.f : 0.f;
            const float mid = 0.5f * (s0 + s1);
            const float dzz = z1 - z0;
            const float cv0 = (s1 - s0) * rcp_nr(dzz + 1e-5f);
            float cv = fminf(prevc, cv0);
            prevc = cv0;
            cv = fminf(fmaxf(cv, -1000.f), 0.f) * inside;

            const float q  = cv * (dzz * 0.5f);
            const float ap = (mid - q) * iv;
            const float an = (mid + q) * iv;
            const float a = exp_fast_f(fminf(fmaxf(-ap, -40.f), 40.f));
            const float b = exp_fast_f(fminf(fmaxf(-an, -40.f), 40.f));
            const float onea = 1.f + a;
            const float P  = onea * (1.f + b);
            const float Nn = __builtin_fmaf(1e-5f, P, b - a);
            const float Dd = __builtin_fmaf(1e-5f, P, 1.f + b);
            const float invD = rcp_nr(Dd);
            const float alpha = Nn * invD;                     // in [0,1]
            const float w = __builtin_fmaf(alpha, trans, 1e-5f);
            trans *= __builtin_fmaf(onea, invD, 1e-7f);        // (1-alpha+1e-7)
            cum += w;
            E[eb + j + 1] = cum;

            z0 = z1; s0 = s1; inner0 = inner1;
        }
        __syncthreads();
    }

    // =================== pass B-1: 16 binary searches ===================
    const float invT = 1.0f / cum;           // cum >= 63e-5 > 0
    int inds[NIMP];
    #pragma unroll
    for (int k = 0; k < NIMP; ++k) {
        const float u = __builtin_fmaf((float)k, 0.0625f, 0.03125f);  // exact
        int lo = 0, hi = 64;
        #pragma unroll
        for (int it = 0; it < 7; ++it) {
            const int m = (lo + hi) >> 1;              // <= 64 (pad slot ok)
            const float cm = E[eb + m] * invT;
            if (lo < hi) { if (cm <= u) lo = m + 1; else hi = m; }
        }
        inds[k] = lo;                                   // in [1,63]
    }

    // =================== pass B-2: chunked emission ===================
    float res[NIMP];
    #pragma unroll
    for (int k = 0; k < NIMP; ++k) res[k] = 0.f;

    #pragma unroll 1
    for (int g = 0; g < 4; ++g) {
        const int jb = g * 16;
        #pragma unroll
        for (int r4 = 0; r4 < 16; ++r4) {
            const int row = r4 * 4 + (t >> 4);
            const int col = t & 15;
            const int rr  = ray0 + row;
            zC[row][col] = (rr < B) ? z_vals[(size_t)rr * 64 + jb + col] : 0.0f;
        }
        if (g < 3) zC[t][16] = live ? z_vals[(size_t)ray * 64 + jb + 16] : 0.0f;
        __syncthreads();

        #pragma unroll
        for (int k = 0; k < NIMP; ++k) {
            const int bel = inds[k] - 1;               // 0..62
            if (bel >= jb && bel < jb + 16) {
                const float u  = __builtin_fmaf((float)k, 0.0625f, 0.03125f);
                const float cb = E[eb + bel] * invT;
                const float ca = E[eb + bel + 1] * invT;
                const float zb = zC[t][bel - jb];
                const float za = zC[t][bel - jb + 1];
                float denom = ca - cb;                 // > 0
                int f = (denom < 4e-3f);               // thin selected bin
                // near-boundary with thin far-side bin (covers ref bin flips)
                const int bm = max(bel - 1, 0);
                const int ap2 = min(inds[k] + 1, 63);
                const float wl = (E[eb + bel] - E[eb + bm]) * invT;
                const float wr = (E[eb + ap2] - E[eb + bel + 1]) * invT;
                f |= ((u - cb) < 4e-5f) & (wl < 4e-3f);
                f |= ((ca - u) < 4e-5f) & (wr < 4e-3f);
                flag |= f;
                denom = (denom < 1e-5f) ? 1.0f : denom;
                const float tt = (u - cb) * rcp_nr(denom);
                res[k] = __builtin_fmaf(tt, za - zb, zb);
            }
        }
        __syncthreads();
    }

    if (live) {
        float4* o4 = (float4*)(out + (size_t)ray * NIMP);
        o4[0] = make_float4(res[0],  res[1],  res[2],  res[3]);
        o4[1] = make_float4(res[4],  res[5],  res[6],  res[7]);
        o4[2] = make_float4(res[8],  res[9],  res[10], res[11]);
        o4[3] = make_float4(res[12], res[13], res[14], res[15]);
        if (flag) {
            const unsigned idx = atomicAdd(ctr, 1u);
            if (idx < cap) list[idx] = (unsigned)ray;
        }
    }
}

// ============================================================================
// Kernel 2: validated r4 f64 wave-per-ray redo over the flagged-ray list.
// forceAll: process every ray (generic/overflow fallback).
// ============================================================================
__global__ __launch_bounds__(256) void neus_redo_kernel(
    const float* __restrict__ rays_o,
    const float* __restrict__ rays_d,
    const float* __restrict__ z_vals,
    const float* __restrict__ sdf,
    const float* __restrict__ inv_s,
    float* __restrict__ out,
    const unsigned* __restrict__ ctr,
    const unsigned* __restrict__ list,
    unsigned cap, int forceAll, int B, int n_imp, double u0, double du)
{
    const int lane = threadIdx.x & 63;
    const int wv   = blockIdx.x * 4 + (threadIdx.x >> 6);
    unsigned count = 0; bool over = true;
    if (!forceAll) {
        count = *ctr;
        over  = count > cap;
    }
    const unsigned nwork = over ? (unsigned)B : count;

    for (unsigned i = wv; i < nwork; i += 1024) {
        const int ray = over ? (int)i : (int)list[i];

        const double z = (double)z_vals[(size_t)ray * 64 + lane];
        const double s = (double)sdf   [(size_t)ray * 64 + lane];
        double isv = 0.0;
        if (lane < 63) isv = (double)inv_s[(size_t)ray * 63 + lane];

        const double ox = (double)rays_o[(size_t)ray*3+0];
        const double oy = (double)rays_o[(size_t)ray*3+1];
        const double oz = (double)rays_o[(size_t)ray*3+2];
        const double dx = (double)rays_d[(size_t)ray*3+0];
        const double dy = (double)rays_d[(size_t)ray*3+1];
        const double dz = (double)rays_d[(size_t)ray*3+2];

        const double px = ox + dx*z, py = oy + dy*z, pz = oz + dz*z;
        const double inner = (fabs(px) <= SIDE && fabs(py) <= SIDE && fabs(pz) <= SIDE) ? 1.0 : 0.0;

        const double next_s  = __shfl_down(s, 1);
        const double next_z  = __shfl_down(z, 1);
        const double inner_n = __shfl_down(inner, 1);

        const double inside = ((inner > 0.5) || (inner_n > 0.5)) ? 1.0 : 0.0;
        const double mid    = 0.5 * (s + next_s);
        const double cv0    = (next_s - s) / (next_z - z + 1e-5);
        double prevc = __shfl_up(cv0, 1);
        if (lane == 0) prevc = 0.0;
        double cv = fmin(prevc, cv0);
        cv = fmin(fmax(cv, -1000.0), 0.0) * inside;
        const double dist = next_z - z;

        const double arg_p = (mid - cv * dist * 0.5) * isv;
        const double arg_n = (mid + cv * dist * 0.5) * isv;
        const double a = exp_fast(fmin(fmax(-arg_p, -350.0), 350.0));
        const double b = exp_fast(fmin(fmax(-arg_n, -350.0), 350.0));
        const double P = (1.0 + a) * (1.0 + b);
        const double alpha = (__builtin_fma(1e-5, P, b - a)) /
                             (__builtin_fma(1e-5, P, 1.0 + b));

        double g = (lane < 63) ? (1.0 - alpha + 1e-7) : 1.0;
        double p = g;
        #pragma unroll
        for (int off = 1; off < 64; off <<= 1) {
            double tmp = __shfl_up(p, off);
            if (lane >= off) p *= tmp;
        }
        double trans = __shfl_up(p, 1);
        if (lane == 0) trans = 1.0;

        const double w = (lane < 63) ? (alpha * trans + 1e-5) : 0.0;

        double sc = w;
        #pragma unroll
        for (int off = 1; off < 64; off <<= 1) {
            double tmp = __shfl_up(sc, off);
            if (lane >= off) sc += tmp;
        }
        const double total = __shfl(sc, 63);
        const double excl  = sc - w;
        const double cdf   = excl / total;

        const double u = u0 + du * (double)lane;
        int lo = 0, hi = 64;
        #pragma unroll
        for (int it = 0; it < 7; ++it) {
            const int m  = (lo + hi) >> 1;
            const double cm = __shfl(cdf, m);
            if (lo < hi) {
                if (cm <= u) lo = m + 1; else hi = m;
            }
        }
        const int ind   = lo;
        const int below = max(ind - 1, 0);
        const int above = min(ind, 63);

        const double cb = __shfl(cdf, below);
        const double ca = __shfl(cdf, above);
        const double bb = __shfl(z, below);
        const double ba = __shfl(z, above);

        double denom = ca - cb;
        denom = (denom < 1e-5) ? 1.0 : denom;
        const double tt  = (u - cb) / denom;
        const double r2  = bb + tt * (ba - bb);

        if (lane < n_imp) out[(size_t)ray * n_imp + lane] = (float)r2;
    }
}

extern "C" void kernel_launch(void* const* d_in, const int* in_sizes, int n_in,
                              void* d_out, int out_size, void* d_ws, size_t ws_size,
                              hipStream_t stream) {
    const float* rays_o = (const float*)d_in[0];
    const float* rays_d = (const float*)d_in[1];
    const float* z_vals = (const float*)d_in[2];
    const float* sdf    = (const float*)d_in[3];
    const float* inv_s  = (const float*)d_in[4];
    float* out = (float*)d_out;

    const int B = in_sizes[0] / 3;          // 131072
    const int n = out_size / B;             // n_importance = 16
    const double u0 = 0.5 / (double)n;
    const double du = (n > 1) ? ((1.0 - 1.0 / (double)n) / (double)(n - 1)) : 0.0;

    unsigned* ctr  = (unsigned*)d_ws;
    unsigned* list = (unsigned*)d_ws + 4;

    if (n == NIMP && (B & 63) == 0 && ws_size >= 64) {
        const unsigned cap = (unsigned)((ws_size - 16) / 4);
        hipMemsetAsync(d_ws, 0, 16, stream);
        neus_fast_kernel<<<B / 64, 64, 0, stream>>>(
            rays_o, rays_d, z_vals, sdf, inv_s, out, ctr, list, cap, B);
        neus_redo_kernel<<<256, 256, 0, stream>>>(
            rays_o, rays_d, z_vals, sdf, inv_s, out, ctr, list, cap, 0, B, n, u0, du);
    } else {
        // generic fallback: full f64 redo over all rays (validated r4 path)
        neus_redo_kernel<<<256, 256, 0, stream>>>(
            rays_o, rays_d, z_vals, sdf, inv_s, out, ctr, list, 0u, 1, B, n, u0, du);
    }
}

// Round 8
// 99.487 us; speedup vs baseline: 1.6103x; 1.6103x over previous
//
#include <hip/hip_runtime.h>
#include <math.h>

#define SIDE 0.6
#define NIMP 16

// ---------- fast f64 exp, |x| <= 350, rel err ~1e-15 (validated r3/r4) ----------
__device__ __forceinline__ double exp_fast(double x) {
    const double INVLN2 = 1.44269504088896338700e+00;
    const double LN2HI  = 6.93147180369123816490e-01;
    const double LN2LO  = 1.90821492927058770002e-10;
    const double kd = __builtin_rint(x * INVLN2);
    const int    k  = (int)kd;
    double r = __builtin_fma(-kd, LN2HI, x);
    r        = __builtin_fma(-kd, LN2LO, r);
    double p =               2.08767569878681e-09;
    p = __builtin_fma(p, r,  2.50521083854417e-08);
    p = __builtin_fma(p, r,  2.75573192239859e-07);
    p = __builtin_fma(p, r,  2.75573192239859e-06);
    p = __builtin_fma(p, r,  2.48015873015873e-05);
    p = __builtin_fma(p, r,  1.98412698412698e-04);
    p = __builtin_fma(p, r,  1.38888888888889e-03);
    p = __builtin_fma(p, r,  8.33333333333333e-03);
    p = __builtin_fma(p, r,  4.16666666666667e-02);
    p = __builtin_fma(p, r,  1.66666666666667e-01);
    p = __builtin_fma(p, r,  5.00000000000000e-01);
    p = __builtin_fma(p, r,  1.0);
    p = __builtin_fma(p, r,  1.0);
    const long long bits = (long long)(1023 + k) << 52;
    return p * __longlong_as_double(bits);
}

// ---------- fast f32 exp, |x| <= 40, rel err ~2e-7 (validated r5/r7) ----------
__device__ __forceinline__ float exp_fast_f(float x) {
    const float kd = rintf(x * 1.44269504f);
    const int   k  = (int)kd;
    float r = __builtin_fmaf(-kd, 0.693359375f, x);
    r       = __builtin_fmaf(kd, 2.12194440e-4f, r);
    float p =                1.98412698e-4f;
    p = __builtin_fmaf(p, r, 1.38888889e-3f);
    p = __builtin_fmaf(p, r, 8.33333333e-3f);
    p = __builtin_fmaf(p, r, 4.16666667e-2f);
    p = __builtin_fmaf(p, r, 1.66666667e-1f);
    p = __builtin_fmaf(p, r, 5.00000000e-1f);
    p = __builtin_fmaf(p, r, 1.0f);
    p = __builtin_fmaf(p, r, 1.0f);
    return p * __int_as_float((127 + k) << 23);
}

#if __has_builtin(__builtin_amdgcn_rcpf)
__device__ __forceinline__ float rcp_nr(float x) {   // ~0.5 ulp: v_rcp + 1 NR
    float r = __builtin_amdgcn_rcpf(x);
    return __builtin_fmaf(__builtin_fmaf(-x, r, 1.0f), r, r);
}
#else
__device__ __forceinline__ float rcp_nr(float x) { return 1.0f / x; }
#endif

// ============================================================================
// Streaming scan over the 63 intervals of one ray (thread-per-ray, no LDS).
// !EMIT: returns total = sum of weights (pass A).
// EMIT : recomputes weights in the IDENTICAL op order (prefix is bitwise equal
//        to pass A's total at the end) and merge-emits the 16 samples as the
//        running prefix crosses U_k = u_k * total. Flags flip-risk per the
//        validated r5/r7 bands.
// ============================================================================
template<bool EMIT>
__device__ __forceinline__ float neus_scan(
    const float* __restrict__ zp, const float* __restrict__ sp,
    const float* __restrict__ ip,
    float ox, float oy, float oz, float dx, float dy, float dz,
    float Ttot, float* __restrict__ out_row, int& flag)
{
    float T = 1.f, cum = 0.f, prevc = 0.f, inner0 = 0.f;
    float carryZ = 0.f, carryS = 0.f, carryIv = 0.f;
    int k = 0;
    float U = 0.f, bandU = 0.f, bandW = 0.f, w_prev = 0.f, pend = 1e30f;
    if (EMIT) {
        bandU = 4e-5f * Ttot;          // near-boundary band (normalized 4e-5)
        bandW = 4e-3f * Ttot;          // thin-bin band (normalized 4e-3)
        U = 0.03125f * Ttot;           // u_0 * total
    }

    #pragma unroll 1
    for (int g = 0; g < 4; ++g) {
        // chunk: zz[0]=carry(elem 16g-1), zz[1..16]=elems 16g..16g+15
        float zz[17], ss[17], vv[16];
        #pragma unroll
        for (int q = 0; q < 4; ++q) {
            const float4 a = *reinterpret_cast<const float4*>(zp + g*16 + q*4);
            const float4 b = *reinterpret_cast<const float4*>(sp + g*16 + q*4);
            zz[1+q*4] = a.x; zz[2+q*4] = a.y; zz[3+q*4] = a.z; zz[4+q*4] = a.w;
            ss[1+q*4] = b.x; ss[2+q*4] = b.y; ss[3+q*4] = b.z; ss[4+q*4] = b.w;
        }
        // iv for interval i (= j = 16g-1+i): vv[0]=carry, vv[1..15]=ip[16g..16g+14]
        #pragma unroll
        for (int q = 1; q < 16; ++q) vv[q] = ip[g*16 - 1 + q];
        vv[0] = carryIv;
        zz[0] = carryZ; ss[0] = carryS;
        if (g == 0) { zz[0] = zz[1]; ss[0] = ss[1]; vv[0] = 0.f; }

        #pragma unroll
        for (int i = 0; i < 16; ++i) {
            // g==0,i==0 is a dummy (computes elem0's box test, w forced 0)
            const bool live = (i != 0) || (g != 0);
            const float z0 = zz[i],   s0 = ss[i];
            const float z1 = zz[i+1], s1 = ss[i+1];
            const float iv = vv[i];

            const float px = __builtin_fmaf(dx, z1, ox);
            const float py = __builtin_fmaf(dy, z1, oy);
            const float pz = __builtin_fmaf(dz, z1, oz);
            const float ax = fabsf(px), ay = fabsf(py), az = fabsf(pz);
            const float inner1 = (ax <= 0.6f && ay <= 0.6f && az <= 0.6f) ? 1.f : 0.f;
            flag |= (fabsf(ax-0.6f) < 1e-5f) | (fabsf(ay-0.6f) < 1e-5f) |
                    (fabsf(az-0.6f) < 1e-5f);

            const float inside = ((inner0 > 0.5f) || (inner1 > 0.5f)) ? 1.f : 0.f;
            const float mid = 0.5f * (s0 + s1);
            const float dzz = z1 - z0;
            const float cv0 = (s1 - s0) * rcp_nr(dzz + 1e-5f);
            float cv = fminf(prevc, cv0);
            prevc = cv0;
            cv = fminf(fmaxf(cv, -1000.f), 0.f) * inside;

            const float q2  = cv * (dzz * 0.5f);
            const float apv = (mid - q2) * iv;
            const float anv = (mid + q2) * iv;
            const float ea = exp_fast_f(fminf(fmaxf(-apv, -40.f), 40.f));
            const float eb = exp_fast_f(fminf(fmaxf(-anv, -40.f), 40.f));
            const float onea = 1.f + ea;
            const float Pp  = onea * (1.f + eb);
            const float Nn  = __builtin_fmaf(1e-5f, Pp, eb - ea);
            const float Dd  = __builtin_fmaf(1e-5f, Pp, 1.f + eb);
            const float invD = rcp_nr(Dd);
            const float alpha = Nn * invD;
            const float w    = live ? __builtin_fmaf(alpha, T, 1e-5f) : 0.0f;
            const float gmul = live ? __builtin_fmaf(onea, invD, 1e-7f) : 1.0f;
            T *= gmul;

            if (EMIT) {
                // right-boundary check deferred from previous interval
                if (pend < bandU && w < bandW) flag = 1;
                pend = 1e30f;
                const float Pn = cum + w;
                while (k < NIMP && U < Pn) {
                    flag |= (((U - cum) < bandU) && (w_prev < bandW));
                    flag |= (w < bandW);
                    const float tt = (U - cum) * rcp_nr(w);
                    out_row[k] = __builtin_fmaf(tt, z1 - z0, z0);
                    pend = Pn - U;
                    ++k;
                    U = __builtin_fmaf((float)k, 0.0625f, 0.03125f) * Ttot;
                }
                cum = Pn;              // same op as pass A's cum = cum + w
                w_prev = w;
            } else {
                cum = cum + w;
            }
            inner0 = inner1;
        }
        carryZ = zz[16]; carryS = ss[16];
        carryIv = (g < 3) ? ip[g*16 + 15] : 0.0f;
    }

    if (EMIT && k < NIMP) {            // unreachable (U_15 < cum bitwise); defensive
        flag = 1;
        while (k < NIMP) out_row[k++] = carryZ;
    }
    return cum;
}

__global__ __launch_bounds__(256) void neus_fast_kernel(
    const float* __restrict__ rays_o,
    const float* __restrict__ rays_d,
    const float* __restrict__ z_vals,
    const float* __restrict__ sdf,
    const float* __restrict__ inv_s,
    float* __restrict__ out,
    unsigned* __restrict__ ctr,
    unsigned* __restrict__ list,
    unsigned cap, int B)
{
    const int ray = blockIdx.x * 256 + threadIdx.x;
    if (ray >= B) return;              // no barriers/LDS: divergent exit is fine

    const float* zp = z_vals + (size_t)ray * 64;
    const float* sp = sdf    + (size_t)ray * 64;
    const float* ip = inv_s  + (size_t)ray * 63;

    const float ox = rays_o[(size_t)ray*3+0];
    const float oy = rays_o[(size_t)ray*3+1];
    const float oz = rays_o[(size_t)ray*3+2];
    const float dx = rays_d[(size_t)ray*3+0];
    const float dy = rays_d[(size_t)ray*3+1];
    const float dz = rays_d[(size_t)ray*3+2];

    int flag = 0;
    const float Ttot = neus_scan<false>(zp, sp, ip, ox, oy, oz, dx, dy, dz,
                                        1.0f, nullptr, flag);
    neus_scan<true>(zp, sp, ip, ox, oy, oz, dx, dy, dz,
                    Ttot, out + (size_t)ray * NIMP, flag);

    if (flag) {
        const unsigned idx = atomicAdd(ctr, 1u);
        if (idx < cap) list[idx] = (unsigned)ray;
    }
}

// ============================================================================
// Kernel 2: validated r4/r7 f64 wave-per-ray redo over the flagged-ray list.
// ============================================================================
__global__ __launch_bounds__(256) void neus_redo_kernel(
    const float* __restrict__ rays_o,
    const float* __restrict__ rays_d,
    const float* __restrict__ z_vals,
    const float* __restrict__ sdf,
    const float* __restrict__ inv_s,
    float* __restrict__ out,
    const unsigned* __restrict__ ctr,
    const unsigned* __restrict__ list,
    unsigned cap, int forceAll, int B, int n_imp, double u0, double du)
{
    const int lane = threadIdx.x & 63;
    const int wv   = blockIdx.x * 4 + (threadIdx.x >> 6);
    unsigned count = 0; bool over = true;
    if (!forceAll) {
        count = *ctr;
        over  = count > cap;
    }
    const unsigned nwork = over ? (unsigned)B : count;

    for (unsigned i = wv; i < nwork; i += 1024) {
        const int ray = over ? (int)i : (int)list[i];

        const double z = (double)z_vals[(size_t)ray * 64 + lane];
        const double s = (double)sdf   [(size_t)ray * 64 + lane];
        double isv = 0.0;
        if (lane < 63) isv = (double)inv_s[(size_t)ray * 63 + lane];

        const double ox = (double)rays_o[(size_t)ray*3+0];
        const double oy = (double)rays_o[(size_t)ray*3+1];
        const double oz = (double)rays_o[(size_t)ray*3+2];
        const double dx = (double)rays_d[(size_t)ray*3+0];
        const double dy = (double)rays_d[(size_t)ray*3+1];
        const double dz = (double)rays_d[(size_t)ray*3+2];

        const double px = ox + dx*z, py = oy + dy*z, pz = oz + dz*z;
        const double inner = (fabs(px) <= SIDE && fabs(py) <= SIDE && fabs(pz) <= SIDE) ? 1.0 : 0.0;

        const double next_s  = __shfl_down(s, 1);
        const double next_z  = __shfl_down(z, 1);
        const double inner_n = __shfl_down(inner, 1);

        const double inside = ((inner > 0.5) || (inner_n > 0.5)) ? 1.0 : 0.0;
        const double mid    = 0.5 * (s + next_s);
        const double cv0    = (next_s - s) / (next_z - z + 1e-5);
        double prevc = __shfl_up(cv0, 1);
        if (lane == 0) prevc = 0.0;
        double cv = fmin(prevc, cv0);
        cv = fmin(fmax(cv, -1000.0), 0.0) * inside;
        const double dist = next_z - z;

        const double arg_p = (mid - cv * dist * 0.5) * isv;
        const double arg_n = (mid + cv * dist * 0.5) * isv;
        const double a = exp_fast(fmin(fmax(-arg_p, -350.0), 350.0));
        const double b = exp_fast(fmin(fmax(-arg_n, -350.0), 350.0));
        const double P = (1.0 + a) * (1.0 + b);
        const double alpha = (__builtin_fma(1e-5, P, b - a)) /
                             (__builtin_fma(1e-5, P, 1.0 + b));

        double g = (lane < 63) ? (1.0 - alpha + 1e-7) : 1.0;
        double p = g;
        #pragma unroll
        for (int off = 1; off < 64; off <<= 1) {
            double tmp = __shfl_up(p, off);
            if (lane >= off) p *= tmp;
        }
        double trans = __shfl_up(p, 1);
        if (lane == 0) trans = 1.0;

        const double w = (lane < 63) ? (alpha * trans + 1e-5) : 0.0;

        double sc = w;
        #pragma unroll
        for (int off = 1; off < 64; off <<= 1) {
            double tmp = __shfl_up(sc, off);
            if (lane >= off) sc += tmp;
        }
        const double total = __shfl(sc, 63);
        const double excl  = sc - w;
        const double cdf   = excl / total;

        const double u = u0 + du * (double)lane;
        int lo = 0, hi = 64;
        #pragma unroll
        for (int it = 0; it < 7; ++it) {
            const int m  = (lo + hi) >> 1;
            const double cm = __shfl(cdf, m);
            if (lo < hi) {
                if (cm <= u) lo = m + 1; else hi = m;
            }
        }
        const int ind   = lo;
        const int below = max(ind - 1, 0);
        const int above = min(ind, 63);

        const double cb = __shfl(cdf, below);
        const double ca = __shfl(cdf, above);
        const double bb = __shfl(z, below);
        const double ba = __shfl(z, above);

        double denom = ca - cb;
        denom = (denom < 1e-5) ? 1.0 : denom;
        const double tt  = (u - cb) / denom;
        const double r2  = bb + tt * (ba - bb);

        if (lane < n_imp) out[(size_t)ray * n_imp + lane] = (float)r2;
    }
}

extern "C" void kernel_launch(void* const* d_in, const int* in_sizes, int n_in,
                              void* d_out, int out_size, void* d_ws, size_t ws_size,
                              hipStream_t stream) {
    const float* rays_o = (const float*)d_in[0];
    const float* rays_d = (const float*)d_in[1];
    const float* z_vals = (const float*)d_in[2];
    const float* sdf    = (const float*)d_in[3];
    const float* inv_s  = (const float*)d_in[4];
    float* out = (float*)d_out;

    const int B = in_sizes[0] / 3;          // 131072
    const int n = out_size / B;             // n_importance = 16
    const double u0 = 0.5 / (double)n;
    const double du = (n > 1) ? ((1.0 - 1.0 / (double)n) / (double)(n - 1)) : 0.0;

    unsigned* ctr  = (unsigned*)d_ws;
    unsigned* list = (unsigned*)d_ws + 4;

    if (n == NIMP && ws_size >= 64) {
        const unsigned cap = (unsigned)((ws_size - 16) / 4);
        hipMemsetAsync(d_ws, 0, 16, stream);
        neus_fast_kernel<<<(B + 255) / 256, 256, 0, stream>>>(
            rays_o, rays_d, z_vals, sdf, inv_s, out, ctr, list, cap, B);
        neus_redo_kernel<<<256, 256, 0, stream>>>(
            rays_o, rays_d, z_vals, sdf, inv_s, out, ctr, list, cap, 0, B, n, u0, du);
    } else {
        // generic fallback: full f64 redo over all rays (validated r4 path)
        neus_redo_kernel<<<256, 256, 0, stream>>>(
            rays_o, rays_d, z_vals, sdf, inv_s, out, ctr, list, 0u, 1, B, n, u0, du);
    }
}

// Round 9
// 71.303 us; speedup vs baseline: 2.2468x; 1.3953x over previous
//
#include <hip/hip_runtime.h>
#include <math.h>

#define SIDE 0.6
#define NIMP 16

// ---------- fast f64 exp, |x| <= 350, rel err ~1e-15 (validated r3/r4) ----------
__device__ __forceinline__ double exp_fast(double x) {
    const double INVLN2 = 1.44269504088896338700e+00;
    const double LN2HI  = 6.93147180369123816490e-01;
    const double LN2LO  = 1.90821492927058770002e-10;
    const double kd = __builtin_rint(x * INVLN2);
    const int    k  = (int)kd;
    double r = __builtin_fma(-kd, LN2HI, x);
    r        = __builtin_fma(-kd, LN2LO, r);
    double p =               2.08767569878681e-09;
    p = __builtin_fma(p, r,  2.50521083854417e-08);
    p = __builtin_fma(p, r,  2.75573192239859e-07);
    p = __builtin_fma(p, r,  2.75573192239859e-06);
    p = __builtin_fma(p, r,  2.48015873015873e-05);
    p = __builtin_fma(p, r,  1.98412698412698e-04);
    p = __builtin_fma(p, r,  1.38888888888889e-03);
    p = __builtin_fma(p, r,  8.33333333333333e-03);
    p = __builtin_fma(p, r,  4.16666666666667e-02);
    p = __builtin_fma(p, r,  1.66666666666667e-01);
    p = __builtin_fma(p, r,  5.00000000000000e-01);
    p = __builtin_fma(p, r,  1.0);
    p = __builtin_fma(p, r,  1.0);
    const long long bits = (long long)(1023 + k) << 52;
    return p * __longlong_as_double(bits);
}

// ---------- fast f32 exp, |x| <= 40, rel err ~2e-7 (validated r5/r7/r8) ----------
__device__ __forceinline__ float exp_fast_f(float x) {
    const float kd = rintf(x * 1.44269504f);
    const int   k  = (int)kd;
    float r = __builtin_fmaf(-kd, 0.693359375f, x);
    r       = __builtin_fmaf(kd, 2.12194440e-4f, r);
    float p =                1.98412698e-4f;
    p = __builtin_fmaf(p, r, 1.38888889e-3f);
    p = __builtin_fmaf(p, r, 8.33333333e-3f);
    p = __builtin_fmaf(p, r, 4.16666667e-2f);
    p = __builtin_fmaf(p, r, 1.66666667e-1f);
    p = __builtin_fmaf(p, r, 5.00000000e-1f);
    p = __builtin_fmaf(p, r, 1.0f);
    p = __builtin_fmaf(p, r, 1.0f);
    return p * __int_as_float((127 + k) << 23);
}

#if __has_builtin(__builtin_amdgcn_rcpf)
__device__ __forceinline__ float rcp_nr(float x) {   // ~0.5 ulp: v_rcp + 1 NR
    float r = __builtin_amdgcn_rcpf(x);
    return __builtin_fmaf(__builtin_fmaf(-x, r, 1.0f), r, r);
}
#else
__device__ __forceinline__ float rcp_nr(float x) { return 1.0f / x; }
#endif

// ============================================================================
// Fast kernel: 4 lanes per ray, 16 intervals per lane, SINGLE pass.
// All weights + z in registers; cross-lane carries via 4-lane shuffles.
// Emission: u_k partitioned across the 4 lanes by canonical boundaries
// B0..B4 (computed identically in every lane -> gap/overlap-free); ulp
// stragglers are force-emitted + flagged. Flip-risk bands (validated
// r5/r8): box +-1e-5, thin-selected-bin 4e-3, near-boundary 4e-5 with
// thin-neighbor 4e-3. Flagged rays -> f64 redo kernel.
// ============================================================================
__global__ __launch_bounds__(256) void neus_fast_kernel(
    const float* __restrict__ rays_o,
    const float* __restrict__ rays_d,
    const float* __restrict__ z_vals,
    const float* __restrict__ sdf,
    const float* __restrict__ inv_s,
    float* __restrict__ out,
    unsigned* __restrict__ ctr,
    unsigned* __restrict__ list,
    unsigned cap, int B)
{
    const int tid  = blockIdx.x * 256 + threadIdx.x;
    const int ray  = tid >> 2;          // 4 lanes per ray
    const int sub  = tid & 3;
    if (ray >= B) return;               // all 4 lanes of a live ray are live

    const float* zp = z_vals + (size_t)ray * 64 + sub * 16;
    const float* sp = sdf    + (size_t)ray * 64 + sub * 16;
    const float* ip = inv_s  + (size_t)ray * 63 + sub * 16;

    const float ox = rays_o[(size_t)ray*3+0];
    const float oy = rays_o[(size_t)ray*3+1];
    const float oz = rays_o[(size_t)ray*3+2];
    const float dx = rays_d[(size_t)ray*3+0];
    const float dy = rays_d[(size_t)ray*3+1];
    const float dz = rays_d[(size_t)ray*3+2];

    // ---- loads: lane-contiguous float4 (stride 64B across lanes) ----
    float z[17], s[17];
    #pragma unroll
    for (int q = 0; q < 4; ++q) {
        const float4 a = *reinterpret_cast<const float4*>(zp + q * 4);
        const float4 b = *reinterpret_cast<const float4*>(sp + q * 4);
        z[q*4+0]=a.x; z[q*4+1]=a.y; z[q*4+2]=a.z; z[q*4+3]=a.w;
        s[q*4+0]=b.x; s[q*4+1]=b.y; s[q*4+2]=b.z; s[q*4+3]=b.w;
    }
    z[16] = __shfl_down(z[0], 1);   // next lane's first elem (sub3: unused)
    s[16] = __shfl_down(s[0], 1);

    float iv[16];
    #pragma unroll
    for (int i = 0; i < 15; ++i) iv[i] = ip[i];
    iv[15] = (sub < 3) ? ip[15] : 0.0f;   // global idx 63 would be OOB

    // ---- inside-box bitmask + box flip band ----
    int flag = 0;
    unsigned m = 0;
    #pragma unroll
    for (int i = 0; i < 16; ++i) {
        const float px = __builtin_fmaf(dx, z[i], ox);
        const float py = __builtin_fmaf(dy, z[i], oy);
        const float pz = __builtin_fmaf(dz, z[i], oz);
        const float ax = fabsf(px), ay = fabsf(py), az = fabsf(pz);
        if (ax <= 0.6f && ay <= 0.6f && az <= 0.6f) m |= (1u << i);
        flag |= (fabsf(ax-0.6f) < 1e-5f) | (fabsf(ay-0.6f) < 1e-5f) |
                (fabsf(az-0.6f) < 1e-5f);
    }
    m |= (__shfl_down(m, 1) & 1u) << 16;   // boundary inner bit (sub3: unused)

    // ---- prev_cos carry across lanes ----
    const float cv0_15 = (s[16]-s[15]) * rcp_nr(z[16]-z[15] + 1e-5f);
    float prevc = __shfl_up(cv0_15, 1);
    if (sub == 0) prevc = 0.0f;

    // ---- per-interval alpha, g ----
    float aw[16], g[16];
    float Gloc = 1.0f;
    #pragma unroll
    for (int i = 0; i < 16; ++i) {
        const float cv0 = (s[i+1]-s[i]) * rcp_nr(z[i+1]-z[i] + 1e-5f);
        float cv = fminf(prevc, cv0);
        prevc = cv0;
        const float inside = ((m >> i) & 3u) ? 1.0f : 0.0f;
        cv = fminf(fmaxf(cv, -1000.f), 0.f) * inside;
        const float mid = 0.5f * (s[i] + s[i+1]);
        const float dzz = z[i+1] - z[i];
        const float q2  = cv * (dzz * 0.5f);
        const float apv = (mid - q2) * iv[i];
        const float anv = (mid + q2) * iv[i];
        const float ea = exp_fast_f(fminf(fmaxf(-apv, -40.f), 40.f));
        const float eb = exp_fast_f(fminf(fmaxf(-anv, -40.f), 40.f));
        const float onea = 1.f + ea;
        const float Pp  = onea * (1.f + eb);
        const float Nn  = __builtin_fmaf(1e-5f, Pp, eb - ea);
        const float Dd  = __builtin_fmaf(1e-5f, Pp, 1.f + eb);
        const float invD = rcp_nr(Dd);
        float al = Nn * invD;
        float gg = __builtin_fmaf(onea, invD, 1e-7f);
        if (i == 15 && sub == 3) { al = 0.f; gg = 1.f; }   // j=63 doesn't exist
        aw[i] = al; g[i] = gg;
        Gloc *= gg;
    }

    // ---- cross-lane transmittance base T0 (left-assoc, consistent) ----
    const int lane = threadIdx.x & 63;
    const int gb   = lane & ~3;
    const float G0 = __shfl(Gloc, gb+0);
    const float G1 = __shfl(Gloc, gb+1);
    const float G2 = __shfl(Gloc, gb+2);
    float T0 = 1.0f;
    if (sub > 0) T0 *= G0;
    if (sub > 1) T0 *= G1;
    if (sub > 2) T0 *= G2;

    // ---- weights + local sum ----
    float Tr = T0, Sloc = 0.0f;
    #pragma unroll
    for (int i = 0; i < 16; ++i) {
        float w = __builtin_fmaf(aw[i], Tr, 1e-5f);
        if (i == 15 && sub == 3) w = 0.0f;
        Tr *= g[i];
        Sloc += w;
        aw[i] = w;                       // aw now holds weights
    }

    // ---- canonical boundaries (identical in all 4 lanes: no gaps) ----
    const float S0 = __shfl(Sloc, gb+0);
    const float S1 = __shfl(Sloc, gb+1);
    const float S2 = __shfl(Sloc, gb+2);
    const float S3 = __shfl(Sloc, gb+3);
    const float B1 = S0;
    const float B2 = B1 + S1;
    const float B3 = B2 + S2;
    const float total = B3 + S3;
    const float Bc  = (sub==0) ? 0.f : (sub==1) ? B1 : (sub==2) ? B2 : B3;
    const float Bc1 = (sub==0) ? B1  : (sub==1) ? B2 : (sub==2) ? B3 : total;
    const float bandU = 4e-5f * total;
    const float bandW = 4e-3f * total;

    // ---- k-range owned by this lane (comparison-based partition) ----
    int ks = 0, ke = 0;
    #pragma unroll
    for (int k = 0; k < NIMP; ++k) {
        const float U = __builtin_fmaf((float)k, 0.0625f, 0.03125f) * total;
        ks += (U < Bc);
        ke += (U < Bc1);
    }

    // boundary-neighbor weights for the flip bands
    float wprevB = __shfl_up(aw[15], 1);
    if (sub == 0) wprevB = 0.0f;           // j=0: conservative (matches r7)
    const float wnextB = __shfl_down(aw[0], 1);  // sub3: garbage, provably unused

    // ---- merge-emission over this lane's intervals ----
    int k = ks;
    float Cprev = Bc;
    float U = __builtin_fmaf((float)k, 0.0625f, 0.03125f) * total;
    #pragma unroll
    for (int i = 0; i < 16; ++i) {
        const float w  = aw[i];
        const float Pn = Cprev + w;
        while (k < ke && U < Pn) {
            const float wprev = (i == 0)  ? wprevB : aw[i-1];
            const float wnext = (i == 15) ? wnextB : aw[i+1];
            flag |= (((U - Cprev) < bandU) & (wprev < bandW));
            flag |= (((Pn - U) < bandU) & (wnext < bandW));
            flag |= (w < bandW);
            const float tt = (U - Cprev) * rcp_nr(w);
            out[(size_t)ray * NIMP + k] = __builtin_fmaf(tt, z[i+1] - z[i], z[i]);
            ++k;
            U = __builtin_fmaf((float)k, 0.0625f, 0.03125f) * total;
        }
        Cprev = Pn;
    }
    while (k < ke) {                        // ulp-crack stragglers -> f64 redo
        flag = 1;
        out[(size_t)ray * NIMP + k] = (sub == 3) ? z[15] : z[16];
        ++k;
    }

    // ---- per-ray flag reduce + list append ----
    int fl = flag;
    fl |= __shfl_xor(fl, 1);
    fl |= __shfl_xor(fl, 2);
    if (sub == 0 && fl) {
        const unsigned idx = atomicAdd(ctr, 1u);
        if (idx < cap) list[idx] = (unsigned)ray;
    }
}

// ============================================================================
// Kernel 2: validated r4/r7 f64 wave-per-ray redo over the flagged-ray list.
// ============================================================================
__global__ __launch_bounds__(256) void neus_redo_kernel(
    const float* __restrict__ rays_o,
    const float* __restrict__ rays_d,
    const float* __restrict__ z_vals,
    const float* __restrict__ sdf,
    const float* __restrict__ inv_s,
    float* __restrict__ out,
    const unsigned* __restrict__ ctr,
    const unsigned* __restrict__ list,
    unsigned cap, int forceAll, int B, int n_imp, double u0, double du)
{
    const int lane = threadIdx.x & 63;
    const int wv   = blockIdx.x * 4 + (threadIdx.x >> 6);
    unsigned count = 0; bool over = true;
    if (!forceAll) {
        count = *ctr;
        over  = count > cap;
    }
    const unsigned nwork = over ? (unsigned)B : count;

    for (unsigned i = wv; i < nwork; i += 1024) {
        const int ray = over ? (int)i : (int)list[i];

        const double z = (double)z_vals[(size_t)ray * 64 + lane];
        const double s = (double)sdf   [(size_t)ray * 64 + lane];
        double isv = 0.0;
        if (lane < 63) isv = (double)inv_s[(size_t)ray * 63 + lane];

        const double ox = (double)rays_o[(size_t)ray*3+0];
        const double oy = (double)rays_o[(size_t)ray*3+1];
        const double oz = (double)rays_o[(size_t)ray*3+2];
        const double dx = (double)rays_d[(size_t)ray*3+0];
        const double dy = (double)rays_d[(size_t)ray*3+1];
        const double dz = (double)rays_d[(size_t)ray*3+2];

        const double px = ox + dx*z, py = oy + dy*z, pz = oz + dz*z;
        const double inner = (fabs(px) <= SIDE && fabs(py) <= SIDE && fabs(pz) <= SIDE) ? 1.0 : 0.0;

        const double next_s  = __shfl_down(s, 1);
        const double next_z  = __shfl_down(z, 1);
        const double inner_n = __shfl_down(inner, 1);

        const double inside = ((inner > 0.5) || (inner_n > 0.5)) ? 1.0 : 0.0;
        const double mid    = 0.5 * (s + next_s);
        const double cv0    = (next_s - s) / (next_z - z + 1e-5);
        double prevc = __shfl_up(cv0, 1);
        if (lane == 0) prevc = 0.0;
        double cv = fmin(prevc, cv0);
        cv = fmin(fmax(cv, -1000.0), 0.0) * inside;
        const double dist = next_z - z;

        const double arg_p = (mid - cv * dist * 0.5) * isv;
        const double arg_n = (mid + cv * dist * 0.5) * isv;
        const double a = exp_fast(fmin(fmax(-arg_p, -350.0), 350.0));
        const double b = exp_fast(fmin(fmax(-arg_n, -350.0), 350.0));
        const double P = (1.0 + a) * (1.0 + b);
        const double alpha = (__builtin_fma(1e-5, P, b - a)) /
                             (__builtin_fma(1e-5, P, 1.0 + b));

        double g = (lane < 63) ? (1.0 - alpha + 1e-7) : 1.0;
        double p = g;
        #pragma unroll
        for (int off = 1; off < 64; off <<= 1) {
            double tmp = __shfl_up(p, off);
            if (lane >= off) p *= tmp;
        }
        double trans = __shfl_up(p, 1);
        if (lane == 0) trans = 1.0;

        const double w = (lane < 63) ? (alpha * trans + 1e-5) : 0.0;

        double sc = w;
        #pragma unroll
        for (int off = 1; off < 64; off <<= 1) {
            double tmp = __shfl_up(sc, off);
            if (lane >= off) sc += tmp;
        }
        const double total = __shfl(sc, 63);
        const double excl  = sc - w;
        const double cdf   = excl / total;

        const double u = u0 + du * (double)lane;
        int lo = 0, hi = 64;
        #pragma unroll
        for (int it = 0; it < 7; ++it) {
            const int m  = (lo + hi) >> 1;
            const double cm = __shfl(cdf, m);
            if (lo < hi) {
                if (cm <= u) lo = m + 1; else hi = m;
            }
        }
        const int ind   = lo;
        const int below = max(ind - 1, 0);
        const int above = min(ind, 63);

        const double cb = __shfl(cdf, below);
        const double ca = __shfl(cdf, above);
        const double bb = __shfl(z, below);
        const double ba = __shfl(z, above);

        double denom = ca - cb;
        denom = (denom < 1e-5) ? 1.0 : denom;
        const double tt  = (u - cb) / denom;
        const double r2  = bb + tt * (ba - bb);

        if (lane < n_imp) out[(size_t)ray * n_imp + lane] = (float)r2;
    }
}

extern "C" void kernel_launch(void* const* d_in, const int* in_sizes, int n_in,
                              void* d_out, int out_size, void* d_ws, size_t ws_size,
                              hipStream_t stream) {
    const float* rays_o = (const float*)d_in[0];
    const float* rays_d = (const float*)d_in[1];
    const float* z_vals = (const float*)d_in[2];
    const float* sdf    = (const float*)d_in[3];
    const float* inv_s  = (const float*)d_in[4];
    float* out = (float*)d_out;

    const int B = in_sizes[0] / 3;          // 131072
    const int n = out_size / B;             // n_importance = 16
    const double u0 = 0.5 / (double)n;
    const double du = (n > 1) ? ((1.0 - 1.0 / (double)n) / (double)(n - 1)) : 0.0;

    unsigned* ctr  = (unsigned*)d_ws;
    unsigned* list = (unsigned*)d_ws + 4;

    if (n == NIMP && ws_size >= 64) {
        const unsigned cap = (unsigned)((ws_size - 16) / 4);
        hipMemsetAsync(d_ws, 0, 16, stream);
        const int threads = B * 4;
        neus_fast_kernel<<<(threads + 255) / 256, 256, 0, stream>>>(
            rays_o, rays_d, z_vals, sdf, inv_s, out, ctr, list, cap, B);
        neus_redo_kernel<<<256, 256, 0, stream>>>(
            rays_o, rays_d, z_vals, sdf, inv_s, out, ctr, list, cap, 0, B, n, u0, du);
    } else {
        // generic fallback: full f64 redo over all rays (validated r4 path)
        neus_redo_kernel<<<256, 256, 0, stream>>>(
            rays_o, rays_d, z_vals, sdf, inv_s, out, ctr, list, 0u, 1, B, n, u0, du);
    }
}

// Round 10
// 70.732 us; speedup vs baseline: 2.2650x; 1.0081x over previous
//
#include <hip/hip_runtime.h>
#include <math.h>

#define SIDE 0.6
#define NIMP 16

// ---------- fast f64 exp, |x| <= 350, rel err ~1e-15 (validated r3/r4) ----------
__device__ __forceinline__ double exp_fast(double x) {
    const double INVLN2 = 1.44269504088896338700e+00;
    const double LN2HI  = 6.93147180369123816490e-01;
    const double LN2LO  = 1.90821492927058770002e-10;
    const double kd = __builtin_rint(x * INVLN2);
    const int    k  = (int)kd;
    double r = __builtin_fma(-kd, LN2HI, x);
    r        = __builtin_fma(-kd, LN2LO, r);
    double p =               2.08767569878681e-09;
    p = __builtin_fma(p, r,  2.50521083854417e-08);
    p = __builtin_fma(p, r,  2.75573192239859e-07);
    p = __builtin_fma(p, r,  2.75573192239859e-06);
    p = __builtin_fma(p, r,  2.48015873015873e-05);
    p = __builtin_fma(p, r,  1.98412698412698e-04);
    p = __builtin_fma(p, r,  1.38888888888889e-03);
    p = __builtin_fma(p, r,  8.33333333333333e-03);
    p = __builtin_fma(p, r,  4.16666666666667e-02);
    p = __builtin_fma(p, r,  1.66666666666667e-01);
    p = __builtin_fma(p, r,  5.00000000000000e-01);
    p = __builtin_fma(p, r,  1.0);
    p = __builtin_fma(p, r,  1.0);
    const long long bits = (long long)(1023 + k) << 52;
    return p * __longlong_as_double(bits);
}

// ---------- fast f32 exp, |x| <= 40, rel err ~2e-7 (validated r5/r7/r8/r9) ----------
__device__ __forceinline__ float exp_fast_f(float x) {
    const float kd = rintf(x * 1.44269504f);
    const int   k  = (int)kd;
    float r = __builtin_fmaf(-kd, 0.693359375f, x);
    r       = __builtin_fmaf(kd, 2.12194440e-4f, r);
    float p =                1.98412698e-4f;
    p = __builtin_fmaf(p, r, 1.38888889e-3f);
    p = __builtin_fmaf(p, r, 8.33333333e-3f);
    p = __builtin_fmaf(p, r, 4.16666667e-2f);
    p = __builtin_fmaf(p, r, 1.66666667e-1f);
    p = __builtin_fmaf(p, r, 5.00000000e-1f);
    p = __builtin_fmaf(p, r, 1.0f);
    p = __builtin_fmaf(p, r, 1.0f);
    return p * __int_as_float((127 + k) << 23);
}

#if __has_builtin(__builtin_amdgcn_rcpf)
__device__ __forceinline__ float rcp_nr(float x) {   // ~0.5 ulp: v_rcp + 1 NR
    float r = __builtin_amdgcn_rcpf(x);
    return __builtin_fmaf(__builtin_fmaf(-x, r, 1.0f), r, r);
}
#else
__device__ __forceinline__ float rcp_nr(float x) { return 1.0f / x; }
#endif

// ============================================================================
// Fast kernel: 4 lanes per ray, 16 intervals per lane, SINGLE pass.
// Identical numerics to round 9. ONLY change: __launch_bounds__(256, 4)
// raises the VGPR cap 64 -> 128 so the per-interval arrays
// (z[17], s[17], iv[16], aw[16], g[16] ~ 100 live VGPRs) stay in registers
// instead of spilling to scratch (r9: VGPR_Count=64 -> spill -> 8x slowdown).
// ============================================================================
__global__ __launch_bounds__(256, 4) void neus_fast_kernel(
    const float* __restrict__ rays_o,
    const float* __restrict__ rays_d,
    const float* __restrict__ z_vals,
    const float* __restrict__ sdf,
    const float* __restrict__ inv_s,
    float* __restrict__ out,
    unsigned* __restrict__ ctr,
    unsigned* __restrict__ list,
    unsigned cap, int B)
{
    const int tid  = blockIdx.x * 256 + threadIdx.x;
    const int ray  = tid >> 2;          // 4 lanes per ray
    const int sub  = tid & 3;
    if (ray >= B) return;               // all 4 lanes of a live ray are live

    const float* zp = z_vals + (size_t)ray * 64 + sub * 16;
    const float* sp = sdf    + (size_t)ray * 64 + sub * 16;
    const float* ip = inv_s  + (size_t)ray * 63 + sub * 16;

    const float ox = rays_o[(size_t)ray*3+0];
    const float oy = rays_o[(size_t)ray*3+1];
    const float oz = rays_o[(size_t)ray*3+2];
    const float dx = rays_d[(size_t)ray*3+0];
    const float dy = rays_d[(size_t)ray*3+1];
    const float dz = rays_d[(size_t)ray*3+2];

    // ---- loads: lane-contiguous float4 (stride 64B across lanes) ----
    float z[17], s[17];
    #pragma unroll
    for (int q = 0; q < 4; ++q) {
        const float4 a = *reinterpret_cast<const float4*>(zp + q * 4);
        const float4 b = *reinterpret_cast<const float4*>(sp + q * 4);
        z[q*4+0]=a.x; z[q*4+1]=a.y; z[q*4+2]=a.z; z[q*4+3]=a.w;
        s[q*4+0]=b.x; s[q*4+1]=b.y; s[q*4+2]=b.z; s[q*4+3]=b.w;
    }
    z[16] = __shfl_down(z[0], 1);   // next lane's first elem (sub3: unused)
    s[16] = __shfl_down(s[0], 1);

    float iv[16];
    #pragma unroll
    for (int i = 0; i < 15; ++i) iv[i] = ip[i];
    iv[15] = (sub < 3) ? ip[15] : 0.0f;   // global idx 63 would be OOB

    // ---- inside-box bitmask + box flip band ----
    int flag = 0;
    unsigned m = 0;
    #pragma unroll
    for (int i = 0; i < 16; ++i) {
        const float px = __builtin_fmaf(dx, z[i], ox);
        const float py = __builtin_fmaf(dy, z[i], oy);
        const float pz = __builtin_fmaf(dz, z[i], oz);
        const float ax = fabsf(px), ay = fabsf(py), az = fabsf(pz);
        if (ax <= 0.6f && ay <= 0.6f && az <= 0.6f) m |= (1u << i);
        flag |= (fabsf(ax-0.6f) < 1e-5f) | (fabsf(ay-0.6f) < 1e-5f) |
                (fabsf(az-0.6f) < 1e-5f);
    }
    m |= (__shfl_down(m, 1) & 1u) << 16;   // boundary inner bit (sub3: unused)

    // ---- prev_cos carry across lanes ----
    const float cv0_15 = (s[16]-s[15]) * rcp_nr(z[16]-z[15] + 1e-5f);
    float prevc = __shfl_up(cv0_15, 1);
    if (sub == 0) prevc = 0.0f;

    // ---- per-interval alpha, g ----
    float aw[16], g[16];
    float Gloc = 1.0f;
    #pragma unroll
    for (int i = 0; i < 16; ++i) {
        const float cv0 = (s[i+1]-s[i]) * rcp_nr(z[i+1]-z[i] + 1e-5f);
        float cv = fminf(prevc, cv0);
        prevc = cv0;
        const float inside = ((m >> i) & 3u) ? 1.0f : 0.0f;
        cv = fminf(fmaxf(cv, -1000.f), 0.f) * inside;
        const float mid = 0.5f * (s[i] + s[i+1]);
        const float dzz = z[i+1] - z[i];
        const float q2  = cv * (dzz * 0.5f);
        const float apv = (mid - q2) * iv[i];
        const float anv = (mid + q2) * iv[i];
        const float ea = exp_fast_f(fminf(fmaxf(-apv, -40.f), 40.f));
        const float eb = exp_fast_f(fminf(fmaxf(-anv, -40.f), 40.f));
        const float onea = 1.f + ea;
        const float Pp  = onea * (1.f + eb);
        const float Nn  = __builtin_fmaf(1e-5f, Pp, eb - ea);
        const float Dd  = __builtin_fmaf(1e-5f, Pp, 1.f + eb);
        const float invD = rcp_nr(Dd);
        float al = Nn * invD;
        float gg = __builtin_fmaf(onea, invD, 1e-7f);
        if (i == 15 && sub == 3) { al = 0.f; gg = 1.f; }   // j=63 doesn't exist
        aw[i] = al; g[i] = gg;
        Gloc *= gg;
    }

    // ---- cross-lane transmittance base T0 (left-assoc, consistent) ----
    const int lane = threadIdx.x & 63;
    const int gb   = lane & ~3;
    const float G0 = __shfl(Gloc, gb+0);
    const float G1 = __shfl(Gloc, gb+1);
    const float G2 = __shfl(Gloc, gb+2);
    float T0 = 1.0f;
    if (sub > 0) T0 *= G0;
    if (sub > 1) T0 *= G1;
    if (sub > 2) T0 *= G2;

    // ---- weights + local sum ----
    float Tr = T0, Sloc = 0.0f;
    #pragma unroll
    for (int i = 0; i < 16; ++i) {
        float w = __builtin_fmaf(aw[i], Tr, 1e-5f);
        if (i == 15 && sub == 3) w = 0.0f;
        Tr *= g[i];
        Sloc += w;
        aw[i] = w;                       // aw now holds weights
    }

    // ---- canonical boundaries (identical in all 4 lanes: no gaps) ----
    const float S0 = __shfl(Sloc, gb+0);
    const float S1 = __shfl(Sloc, gb+1);
    const float S2 = __shfl(Sloc, gb+2);
    const float S3 = __shfl(Sloc, gb+3);
    const float B1 = S0;
    const float B2 = B1 + S1;
    const float B3 = B2 + S2;
    const float total = B3 + S3;
    const float Bc  = (sub==0) ? 0.f : (sub==1) ? B1 : (sub==2) ? B2 : B3;
    const float Bc1 = (sub==0) ? B1  : (sub==1) ? B2 : (sub==2) ? B3 : total;
    const float bandU = 4e-5f * total;
    const float bandW = 4e-3f * total;

    // ---- k-range owned by this lane (comparison-based partition) ----
    int ks = 0, ke = 0;
    #pragma unroll
    for (int k = 0; k < NIMP; ++k) {
        const float U = __builtin_fmaf((float)k, 0.0625f, 0.03125f) * total;
        ks += (U < Bc);
        ke += (U < Bc1);
    }

    // boundary-neighbor weights for the flip bands
    float wprevB = __shfl_up(aw[15], 1);
    if (sub == 0) wprevB = 0.0f;           // j=0: conservative (matches r7)
    const float wnextB = __shfl_down(aw[0], 1);  // sub3: garbage, provably unused

    // ---- merge-emission over this lane's intervals ----
    int k = ks;
    float Cprev = Bc;
    float U = __builtin_fmaf((float)k, 0.0625f, 0.03125f) * total;
    #pragma unroll
    for (int i = 0; i < 16; ++i) {
        const float w  = aw[i];
        const float Pn = Cprev + w;
        while (k < ke && U < Pn) {
            const float wprev = (i == 0)  ? wprevB : aw[i-1];
            const float wnext = (i == 15) ? wnextB : aw[i+1];
            flag |= (((U - Cprev) < bandU) & (wprev < bandW));
            flag |= (((Pn - U) < bandU) & (wnext < bandW));
            flag |= (w < bandW);
            const float tt = (U - Cprev) * rcp_nr(w);
            out[(size_t)ray * NIMP + k] = __builtin_fmaf(tt, z[i+1] - z[i], z[i]);
            ++k;
            U = __builtin_fmaf((float)k, 0.0625f, 0.03125f) * total;
        }
        Cprev = Pn;
    }
    while (k < ke) {                        // ulp-crack stragglers -> f64 redo
        flag = 1;
        out[(size_t)ray * NIMP + k] = (sub == 3) ? z[15] : z[16];
        ++k;
    }

    // ---- per-ray flag reduce + list append ----
    int fl = flag;
    fl |= __shfl_xor(fl, 1);
    fl |= __shfl_xor(fl, 2);
    if (sub == 0 && fl) {
        const unsigned idx = atomicAdd(ctr, 1u);
        if (idx < cap) list[idx] = (unsigned)ray;
    }
}

// ============================================================================
// Kernel 2: validated r4/r7 f64 wave-per-ray redo over the flagged-ray list.
// ============================================================================
__global__ __launch_bounds__(256) void neus_redo_kernel(
    const float* __restrict__ rays_o,
    const float* __restrict__ rays_d,
    const float* __restrict__ z_vals,
    const float* __restrict__ sdf,
    const float* __restrict__ inv_s,
    float* __restrict__ out,
    const unsigned* __restrict__ ctr,
    const unsigned* __restrict__ list,
    unsigned cap, int forceAll, int B, int n_imp, double u0, double du)
{
    const int lane = threadIdx.x & 63;
    const int wv   = blockIdx.x * 4 + (threadIdx.x >> 6);
    unsigned count = 0; bool over = true;
    if (!forceAll) {
        count = *ctr;
        over  = count > cap;
    }
    const unsigned nwork = over ? (unsigned)B : count;

    for (unsigned i = wv; i < nwork; i += 1024) {
        const int ray = over ? (int)i : (int)list[i];

        const double z = (double)z_vals[(size_t)ray * 64 + lane];
        const double s = (double)sdf   [(size_t)ray * 64 + lane];
        double isv = 0.0;
        if (lane < 63) isv = (double)inv_s[(size_t)ray * 63 + lane];

        const double ox = (double)rays_o[(size_t)ray*3+0];
        const double oy = (double)rays_o[(size_t)ray*3+1];
        const double oz = (double)rays_o[(size_t)ray*3+2];
        const double dx = (double)rays_d[(size_t)ray*3+0];
        const double dy = (double)rays_d[(size_t)ray*3+1];
        const double dz = (double)rays_d[(size_t)ray*3+2];

        const double px = ox + dx*z, py = oy + dy*z, pz = oz + dz*z;
        const double inner = (fabs(px) <= SIDE && fabs(py) <= SIDE && fabs(pz) <= SIDE) ? 1.0 : 0.0;

        const double next_s  = __shfl_down(s, 1);
        const double next_z  = __shfl_down(z, 1);
        const double inner_n = __shfl_down(inner, 1);

        const double inside = ((inner > 0.5) || (inner_n > 0.5)) ? 1.0 : 0.0;
        const double mid    = 0.5 * (s + next_s);
        const double cv0    = (next_s - s) / (next_z - z + 1e-5);
        double prevc = __shfl_up(cv0, 1);
        if (lane == 0) prevc = 0.0;
        double cv = fmin(prevc, cv0);
        cv = fmin(fmax(cv, -1000.0), 0.0) * inside;
        const double dist = next_z - z;

        const double arg_p = (mid - cv * dist * 0.5) * isv;
        const double arg_n = (mid + cv * dist * 0.5) * isv;
        const double a = exp_fast(fmin(fmax(-arg_p, -350.0), 350.0));
        const double b = exp_fast(fmin(fmax(-arg_n, -350.0), 350.0));
        const double P = (1.0 + a) * (1.0 + b);
        const double alpha = (__builtin_fma(1e-5, P, b - a)) /
                             (__builtin_fma(1e-5, P, 1.0 + b));

        double g = (lane < 63) ? (1.0 - alpha + 1e-7) : 1.0;
        double p = g;
        #pragma unroll
        for (int off = 1; off < 64; off <<= 1) {
            double tmp = __shfl_up(p, off);
            if (lane >= off) p *= tmp;
        }
        double trans = __shfl_up(p, 1);
        if (lane == 0) trans = 1.0;

        const double w = (lane < 63) ? (alpha * trans + 1e-5) : 0.0;

        double sc = w;
        #pragma unroll
        for (int off = 1; off < 64; off <<= 1) {
            double tmp = __shfl_up(sc, off);
            if (lane >= off) sc += tmp;
        }
        const double total = __shfl(sc, 63);
        const double excl  = sc - w;
        const double cdf   = excl / total;

        const double u = u0 + du * (double)lane;
        int lo = 0, hi = 64;
        #pragma unroll
        for (int it = 0; it < 7; ++it) {
            const int m  = (lo + hi) >> 1;
            const double cm = __shfl(cdf, m);
            if (lo < hi) {
                if (cm <= u) lo = m + 1; else hi = m;
            }
        }
        const int ind   = lo;
        const int below = max(ind - 1, 0);
        const int above = min(ind, 63);

        const double cb = __shfl(cdf, below);
        const double ca = __shfl(cdf, above);
        const double bb = __shfl(z, below);
        const double ba = __shfl(z, above);

        double denom = ca - cb;
        denom = (denom < 1e-5) ? 1.0 : denom;
        const double tt  = (u - cb) / denom;
        const double r2  = bb + tt * (ba - bb);

        if (lane < n_imp) out[(size_t)ray * n_imp + lane] = (float)r2;
    }
}

extern "C" void kernel_launch(void* const* d_in, const int* in_sizes, int n_in,
                              void* d_out, int out_size, void* d_ws, size_t ws_size,
                              hipStream_t stream) {
    const float* rays_o = (const float*)d_in[0];
    const float* rays_d = (const float*)d_in[1];
    const float* z_vals = (const float*)d_in[2];
    const float* sdf    = (const float*)d_in[3];
    const float* inv_s  = (const float*)d_in[4];
    float* out = (float*)d_out;

    const int B = in_sizes[0] / 3;          // 131072
    const int n = out_size / B;             // n_importance = 16
    const double u0 = 0.5 / (double)n;
    const double du = (n > 1) ? ((1.0 - 1.0 / (double)n) / (double)(n - 1)) : 0.0;

    unsigned* ctr  = (unsigned*)d_ws;
    unsigned* list = (unsigned*)d_ws + 4;

    if (n == NIMP && ws_size >= 64) {
        const unsigned cap = (unsigned)((ws_size - 16) / 4);
        hipMemsetAsync(d_ws, 0, 16, stream);
        const int threads = B * 4;
        neus_fast_kernel<<<(threads + 255) / 256, 256, 0, stream>>>(
            rays_o, rays_d, z_vals, sdf, inv_s, out, ctr, list, cap, B);
        neus_redo_kernel<<<256, 256, 0, stream>>>(
            rays_o, rays_d, z_vals, sdf, inv_s, out, ctr, list, cap, 0, B, n, u0, du);
    } else {
        // generic fallback: full f64 redo over all rays (validated r4 path)
        neus_redo_kernel<<<256, 256, 0, stream>>>(
            rays_o, rays_d, z_vals, sdf, inv_s, out, ctr, list, 0u, 1, B, n, u0, du);
    }
}